// Round 3
// baseline (597.497 us; speedup 1.0000x reference)
//
#include <hip/hip_runtime.h>
#include <hip/hip_bf16.h>
#include <stdint.h>

typedef __bf16 bf16;
typedef bf16 bf16x8 __attribute__((ext_vector_type(8)));
typedef bf16 bf16x4 __attribute__((ext_vector_type(4)));
typedef float f32x4 __attribute__((ext_vector_type(4)));

#define NQ_    8
#define EMBED_ 1024
#define FFN_   4096
#define MROWS  32768   // B*S = 8*4096
#define NOUT   1024    // EMBED

// ---- async global->LDS, 16B per lane, wave-uniform LDS base ----
__device__ __forceinline__ void gl_lds16(const bf16* g, bf16* l) {
  __builtin_amdgcn_global_load_lds(
      (__attribute__((address_space(1))) void*)(const_cast<bf16*>(g)),
      (__attribute__((address_space(3))) void*)l, 16, 0, 0);
}

// ============================================================
// Kernel 1: W_out f32 -> bf16   (1024*4096 elems, 4/thread)
// ============================================================
__global__ __launch_bounds__(256) void k_wcvt(const float* __restrict__ w,
                                              bf16* __restrict__ wb) {
  const int i = (blockIdx.x * 256 + threadIdx.x) * 4;
  const float4 v = *(const float4*)(w + i);
  bf16x4 o;
  o[0] = (bf16)v.x; o[1] = (bf16)v.y; o[2] = (bf16)v.z; o[3] = (bf16)v.w;
  *(bf16x4*)(wb + i) = o;
}

// ============================================================
// Kernel 2: theta = x @ W_enc^T ; z = analytic circuit expvals
//   z_0 = prod_{w=1..7} cos(theta_w); z_k = prod_{w=0..k} cos(theta_w)
// (Heisenberg: O_0 = Z1..Z7, O_k = Z0..Zk through the CNOT ring)
// ============================================================
__global__ __launch_bounds__(256) void k_encode(const float* __restrict__ x,
                                                const float* __restrict__ Wenc,
                                                float* __restrict__ z) {
  const int t = threadIdx.x;
  const int wave = t >> 6, lane = t & 63;
  const int r0 = blockIdx.x * 16;

  float4 we[8];
#pragma unroll
  for (int q = 0; q < 8; ++q)
    we[q] = *(const float4*)(Wenc + q * EMBED_ + t * 4);

  __shared__ float red[16][4][8];
  __shared__ float cb[16][8];

  for (int rr = 0; rr < 16; ++rr) {
    const float4 xv = *(const float4*)(x + (size_t)(r0 + rr) * EMBED_ + t * 4);
#pragma unroll
    for (int q = 0; q < 8; ++q) {
      float v = xv.x * we[q].x + xv.y * we[q].y + xv.z * we[q].z + xv.w * we[q].w;
#pragma unroll
      for (int off = 32; off > 0; off >>= 1) v += __shfl_xor(v, off, 64);
      if (lane == 0) red[rr][wave][q] = v;
    }
  }
  __syncthreads();
  if (t < 128) {
    const int rr = t >> 3, q = t & 7;
    const float th = red[rr][0][q] + red[rr][1][q] + red[rr][2][q] + red[rr][3][q];
    cb[rr][q] = cosf(th);
  }
  __syncthreads();
  if (t < 16) {
    float c[8];
#pragma unroll
    for (int q = 0; q < 8; ++q) c[q] = cb[t][q];
    float zz[8];
    zz[0] = c[1] * c[2] * c[3] * c[4] * c[5] * c[6] * c[7];
    float p = c[0];
#pragma unroll
    for (int k = 1; k < 8; ++k) { p *= c[k]; zz[k] = p; }
    float4* zp = (float4*)(z + (size_t)(r0 + t) * 8);
    zp[0] = make_float4(zz[0], zz[1], zz[2], zz[3]);
    zp[1] = make_float4(zz[4], zz[5], zz[6], zz[7]);
  }
}

// ============================================================
// Kernel 3: h = relu(z @ W_dec^T) -> bf16 [chunk_rows][4096]
// ============================================================
__global__ __launch_bounds__(256) void k_hgen(const float* __restrict__ z,
                                              const float* __restrict__ Wdec,
                                              bf16* __restrict__ h,
                                              int row0) {
  const int t = threadIdx.x;
  const int f0 = blockIdx.y * 2048 + t * 8;
  const int g0 = row0 + blockIdx.x * 64;  // global row base
  const int l0 = blockIdx.x * 64;         // local row base in h

  float4 wd[16];
#pragma unroll
  for (int i = 0; i < 16; ++i)
    wd[i] = *(const float4*)(Wdec + (size_t)f0 * 8 + i * 4);

  for (int rr = 0; rr < 64; ++rr) {
    const float4* zp = (const float4*)(z + (size_t)(g0 + rr) * 8);
    const float4 z0 = zp[0], z1 = zp[1];
    bf16x8 o;
#pragma unroll
    for (int j = 0; j < 8; ++j) {
      const float4 a = wd[j * 2], b = wd[j * 2 + 1];
      float s = a.x * z0.x + a.y * z0.y + a.z * z0.z + a.w * z0.w +
                b.x * z1.x + b.y * z1.y + b.z * z1.z + b.w * z1.w;
      o[j] = (bf16)fmaxf(s, 0.0f);
    }
    *(bf16x8*)(h + (size_t)(l0 + rr) * FFN_ + f0) = o;
  }
}

// ============================================================
// Kernel 4: out = h @ W_out^T   (m97-structure 128x128 bf16 GEMM)
// A = h [chunk][4096] bf16, Bt = W_out bf16 [1024][4096] (N-major),
// C = out FLOAT32 [32768][1024]  <-- d_out is f32 (ref output dtype)
// ============================================================
__global__ __launch_bounds__(256) void k_gemm(const bf16* __restrict__ A,
                                              const bf16* __restrict__ Bt,
                                              float* __restrict__ C,
                                              int row0) {
  const int K = FFN_;
  __shared__ bf16 As[128 * 32];
  __shared__ bf16 Bs[128 * 32];

  // bijective XCD swizzle (gridDim.x is always a multiple of 8)
  const int cpx = (int)gridDim.x >> 3;
  const int bid = ((int)blockIdx.x & 7) * cpx + ((int)blockIdx.x >> 3);
  const int mi = bid >> 3, ni = bid & 7;

  const int t = threadIdx.x, wave = t >> 6, lane = t & 63;
  const int wr = wave >> 1, wc = wave & 1;

  // staging: thread covers flat 16B chunk t of each 64-row half-tile
  const int srow = t >> 2;          // 0..63
  const int scol = (t & 3) * 8;     // 0,8,16,24
  const bf16* Ag = A + (size_t)(mi * 128 + srow) * K + scol;
  const bf16* Bg = Bt + (size_t)(ni * 128 + srow) * K + scol;
  bf16* Al = As + wave * 512;       // wave-uniform LDS base (1024 B per wave)
  bf16* Bl = Bs + wave * 512;

  const int frow = lane & 15;
  const int fk = (lane >> 4) * 8;

  f32x4 acc[4][4] = {};

  for (int kt = 0; kt < K; kt += 32) {
    gl_lds16(Ag + kt, Al);
    gl_lds16(Ag + kt + (size_t)64 * K, Al + 2048);
    gl_lds16(Bg + kt, Bl);
    gl_lds16(Bg + kt + (size_t)64 * K, Bl + 2048);
    __syncthreads();

    bf16x8 af[4], bfr[4];
#pragma unroll
    for (int m = 0; m < 4; ++m)
      af[m] = *(const bf16x8*)(As + (wr * 64 + m * 16 + frow) * 32 + fk);
#pragma unroll
    for (int n = 0; n < 4; ++n)
      bfr[n] = *(const bf16x8*)(Bs + (wc * 64 + n * 16 + frow) * 32 + fk);

#pragma unroll
    for (int m = 0; m < 4; ++m)
#pragma unroll
      for (int n = 0; n < 4; ++n)
        acc[m][n] = __builtin_amdgcn_mfma_f32_16x16x32_bf16(af[m], bfr[n],
                                                            acc[m][n], 0, 0, 0);
    __syncthreads();
  }

  // C/D layout: col = lane&15, row = (lane>>4)*4 + reg  [m89/m91 verified]
  const int orow = (lane >> 4) * 4, ocol = lane & 15;
  const int rbase = row0 + mi * 128 + wr * 64;
  const int cbase = ni * 128 + wc * 64;
#pragma unroll
  for (int m = 0; m < 4; ++m)
#pragma unroll
    for (int n = 0; n < 4; ++n)
#pragma unroll
      for (int j = 0; j < 4; ++j)
        C[(size_t)(rbase + m * 16 + orow + j) * NOUT + (cbase + n * 16 + ocol)] =
            acc[m][n][j];
}

// ============================================================
extern "C" void kernel_launch(void* const* d_in, const int* in_sizes, int n_in,
                              void* d_out, int out_size, void* d_ws, size_t ws_size,
                              hipStream_t stream) {
  const float* x    = (const float*)d_in[0];
  const float* Wenc = (const float*)d_in[1];
  const float* Wdec = (const float*)d_in[2];
  const float* Wout = (const float*)d_in[3];
  float* out = (float*)d_out;   // reference output dtype is float32

  char* ws = (char*)d_ws;
  bf16*  Wb = (bf16*)ws;                          // 1024*4096*2 = 8 MiB
  float* z  = (float*)(ws + 8388608);             // 32768*8*4   = 1 MiB
  bf16*  h  = (bf16*)(ws + 8388608 + 1048576);    // up to 256 MiB

  const size_t head = 8388608 + 1048576;
  const size_t avail = ws_size > head ? ws_size - head : 0;
  int nch = 1;  // chunk M if the workspace can't hold full h
  while (nch < 256 && (size_t)(MROWS / nch) * FFN_ * 2 > avail) nch <<= 1;
  const int chunk = MROWS / nch;

  k_wcvt<<<4096, 256, 0, stream>>>(Wout, Wb);
  k_encode<<<2048, 256, 0, stream>>>(x, Wenc, z);
  for (int c = 0; c < nch; ++c) {
    const int row0 = c * chunk;
    dim3 hg(chunk / 64, 2);
    k_hgen<<<hg, 256, 0, stream>>>(z, Wdec, h, row0);
    k_gemm<<<(chunk / 128) * 8, 256, 0, stream>>>(h, Wb, out, row0);
  }
}

// Round 4
// 389.971 us; speedup vs baseline: 1.5322x; 1.5322x over previous
//
#include <hip/hip_runtime.h>
#include <hip/hip_bf16.h>
#include <stdint.h>

typedef __bf16 bf16;
typedef bf16 bf16x8 __attribute__((ext_vector_type(8)));
typedef bf16 bf16x4 __attribute__((ext_vector_type(4)));
typedef float f32x4 __attribute__((ext_vector_type(4)));

#define NQ_    8
#define EMBED_ 1024
#define FFN_   4096
#define MROWS  32768   // B*S = 8*4096
#define NOUT   1024    // EMBED
#define NT_    (FFN_ / 64)   // 64 K-tiles of BK=64

// ---- async global->LDS, 16B per lane, wave-uniform LDS base ----
__device__ __forceinline__ void gl_lds16(const bf16* g, bf16* l) {
  __builtin_amdgcn_global_load_lds(
      (__attribute__((address_space(1))) void*)(const_cast<bf16*>(g)),
      (__attribute__((address_space(3))) void*)l, 16, 0, 0);
}

#define BAR()   __builtin_amdgcn_s_barrier()
#define LGKM0() asm volatile("s_waitcnt lgkmcnt(0)" ::: "memory")
#define VM2()   asm volatile("s_waitcnt vmcnt(2)" ::: "memory")
#define VM0()   asm volatile("s_waitcnt vmcnt(0)" ::: "memory")
#define MFMA(a, b, c) __builtin_amdgcn_mfma_f32_16x16x32_bf16((a), (b), (c), 0, 0, 0)

// ============================================================
// Kernel 1: W_out f32 -> bf16
// ============================================================
__global__ __launch_bounds__(256) void k_wcvt(const float* __restrict__ w,
                                              bf16* __restrict__ wb) {
  const int i = (blockIdx.x * 256 + threadIdx.x) * 4;
  const float4 v = *(const float4*)(w + i);
  bf16x4 o;
  o[0] = (bf16)v.x; o[1] = (bf16)v.y; o[2] = (bf16)v.z; o[3] = (bf16)v.w;
  *(bf16x4*)(wb + i) = o;
}

// ============================================================
// Kernel 2: theta = x @ W_enc^T ; z = analytic circuit expvals
//   z_0 = prod_{w=1..7} cos(theta_w); z_k = prod_{w=0..k} cos(theta_w)
// ============================================================
__global__ __launch_bounds__(256) void k_encode(const float* __restrict__ x,
                                                const float* __restrict__ Wenc,
                                                float* __restrict__ z) {
  const int t = threadIdx.x;
  const int wave = t >> 6, lane = t & 63;
  const int r0 = blockIdx.x * 16;

  float4 we[8];
#pragma unroll
  for (int q = 0; q < 8; ++q)
    we[q] = *(const float4*)(Wenc + q * EMBED_ + t * 4);

  __shared__ float red[16][4][8];
  __shared__ float cb[16][8];

  for (int rr = 0; rr < 16; ++rr) {
    const float4 xv = *(const float4*)(x + (size_t)(r0 + rr) * EMBED_ + t * 4);
#pragma unroll
    for (int q = 0; q < 8; ++q) {
      float v = xv.x * we[q].x + xv.y * we[q].y + xv.z * we[q].z + xv.w * we[q].w;
#pragma unroll
      for (int off = 32; off > 0; off >>= 1) v += __shfl_xor(v, off, 64);
      if (lane == 0) red[rr][wave][q] = v;
    }
  }
  __syncthreads();
  if (t < 128) {
    const int rr = t >> 3, q = t & 7;
    const float th = red[rr][0][q] + red[rr][1][q] + red[rr][2][q] + red[rr][3][q];
    cb[rr][q] = cosf(th);
  }
  __syncthreads();
  if (t < 16) {
    float c[8];
#pragma unroll
    for (int q = 0; q < 8; ++q) c[q] = cb[t][q];
    float zz[8];
    zz[0] = c[1] * c[2] * c[3] * c[4] * c[5] * c[6] * c[7];
    float p = c[0];
#pragma unroll
    for (int k = 1; k < 8; ++k) { p *= c[k]; zz[k] = p; }
    float4* zp = (float4*)(z + (size_t)(r0 + t) * 8);
    zp[0] = make_float4(zz[0], zz[1], zz[2], zz[3]);
    zp[1] = make_float4(zz[4], zz[5], zz[6], zz[7]);
  }
}

// ============================================================
// Kernel 3: h = relu(z @ W_dec^T) -> bf16 [chunk_rows][4096]
// ============================================================
__global__ __launch_bounds__(256) void k_hgen(const float* __restrict__ z,
                                              const float* __restrict__ Wdec,
                                              bf16* __restrict__ h,
                                              int row0) {
  const int t = threadIdx.x;
  const int f0 = blockIdx.y * 2048 + t * 8;
  const int g0 = row0 + blockIdx.x * 64;
  const int l0 = blockIdx.x * 64;

  float4 wd[16];
#pragma unroll
  for (int i = 0; i < 16; ++i)
    wd[i] = *(const float4*)(Wdec + (size_t)f0 * 8 + i * 4);

  for (int rr = 0; rr < 64; ++rr) {
    const float4* zp = (const float4*)(z + (size_t)(g0 + rr) * 8);
    const float4 z0 = zp[0], z1 = zp[1];
    bf16x8 o;
#pragma unroll
    for (int j = 0; j < 8; ++j) {
      const float4 a = wd[j * 2], b = wd[j * 2 + 1];
      float s = a.x * z0.x + a.y * z0.y + a.z * z0.z + a.w * z0.w +
                b.x * z1.x + b.y * z1.y + b.z * z1.z + b.w * z1.w;
      o[j] = (bf16)fmaxf(s, 0.0f);
    }
    *(bf16x8*)(h + (size_t)(l0 + rr) * FFN_ + f0) = o;
  }
}

// ============================================================
// Kernel 4: out = h @ W_out^T — 256x256xBK64 8-phase schedule
// (T1 XCD-swizzle + T2 st_16x32 + T3/T4 counted vmcnt + T5 setprio)
// 512 threads = 8 waves (2M x 4N), per-wave 128x64 out, LDS 128 KiB dbuf.
// Schedule ledger (group T computes buf c=T&1):
//   ph1: ds A[m0-3]+B[n0-1] (12) | stage s1(T+1)->o | bar lgkm0 prio MFMA Q0 bar
//   ph2: ds B[n2-3] (4)          | stage s2(T+1)->o | ...            MFMA Q1
//   ph3: ds A[m4-7] (8)          | stage s3(T+1)->o | ...            MFMA Q2
//   ph4: (no ds)                 | stage s0(T+2)->c | bar prio MFMA Q3, vmcnt(2), bar
// s0(T+2)->c is safe: all buf-c ds_reads retired at ph3's lgkmcnt+barrier.
// vmcnt(2) leaves exactly s0(next-next) in flight; vmcnt(0) for T>=NT-2.
// ============================================================
__global__ __launch_bounds__(512, 2) void k_gemm8(const bf16* __restrict__ A,
                                                  const bf16* __restrict__ Bt,
                                                  float* __restrict__ C,
                                                  int row0) {
  __shared__ bf16 lds[65536];  // 128 KiB: buf c at c*32768 elems = [A 16384 | B 16384]

  // bijective XCD swizzle (m204)
  const int nwg = (int)gridDim.x, orig = (int)blockIdx.x;
  const int qd = nwg >> 3, rm = nwg & 7;
  const int xcd = orig & 7;
  const int bid = (xcd < rm ? xcd * (qd + 1) : rm * (qd + 1) + (xcd - rm) * qd) + (orig >> 3);
  const int mi = bid >> 2, ni = bid & 3;

  const int t = threadIdx.x;
  const int wave = t >> 6, lane = t & 63;
  const int wm = wave >> 2, wn = wave & 3;

  // staging geometry: chunk q = i*512 + t ; row = q>>3 ; col8 = (q&7)^colxor
  const int colxor = ((lane >> 5) & 1) << 1;   // pre-swizzled source (st_16x32 involution)
  const int qrow0 = t >> 3, qc8 = t & 7;
  const size_t Abase = (size_t)(mi * 256) * FFN_;
  const size_t Bbase = (size_t)(ni * 256) * FFN_;
  const int wbase = wave * 512;                // wave-uniform LDS base (1024 B/wave)

  const int fr = lane & 15, fk = (lane >> 4) * 8;

  f32x4 acc[8][4] = {};

  auto stage = [&](int s, int T1) {            // s: 0=A rows 0-127, 1=A 128-255, 2=B 0-127, 3=B 128-255
    const int c = T1 & 1;
    const bf16* G = (s < 2) ? A : Bt;
    const size_t gb = ((s < 2) ? Abase : Bbase) + (size_t)((s & 1) * 128) * FFN_ + T1 * 64;
    bf16* L = (bf16*)lds + c * 32768 + ((s < 2) ? 0 : 16384) + (s & 1) * 8192 + wbase;
#pragma unroll
    for (int i = 0; i < 2; ++i) {
      const int row = i * 64 + qrow0;
      const int c8 = qc8 ^ colxor;
      gl_lds16(G + gb + (size_t)row * FFN_ + c8 * 8, L + i * 4096);
    }
  };
  auto ldA = [&](int c, int m, int kk) -> bf16x8 {   // swizzled read: off ^= (row&4)<<2
    const int row = wm * 128 + m * 16 + fr;
    const int off = (row * 64 + kk * 32 + fk) ^ ((row & 4) << 2);
    return *(const bf16x8*)((const bf16*)lds + c * 32768 + off);
  };
  auto ldB = [&](int c, int n, int kk) -> bf16x8 {
    const int row = wn * 64 + n * 16 + fr;
    const int off = (row * 64 + kk * 32 + fk) ^ ((row & 4) << 2);
    return *(const bf16x8*)((const bf16*)lds + c * 32768 + 16384 + off);
  };

  // prologue: tile0 fully + s0 of tile1; wait tile0 (leave 2 in flight)
  stage(0, 0); stage(1, 0); stage(2, 0); stage(3, 0);
  stage(0, 1);
  VM2();
  BAR();

#pragma unroll 2
  for (int T = 0; T < NT_; ++T) {
    const int c = T & 1;
    bf16x8 a[4][2], b[4][2];

    // ---- phase 1: Q0 (m0-3 x n0-1) ----
#pragma unroll
    for (int m = 0; m < 4; ++m) { a[m][0] = ldA(c, m, 0); a[m][1] = ldA(c, m, 1); }
#pragma unroll
    for (int n = 0; n < 2; ++n) { b[n][0] = ldB(c, n, 0); b[n][1] = ldB(c, n, 1); }
    if (T + 1 < NT_) stage(1, T + 1);
    BAR(); LGKM0();
    __builtin_amdgcn_s_setprio(1);
#pragma unroll
    for (int m = 0; m < 4; ++m)
#pragma unroll
      for (int n = 0; n < 2; ++n) {
        acc[m][n] = MFMA(a[m][0], b[n][0], acc[m][n]);
        acc[m][n] = MFMA(a[m][1], b[n][1], acc[m][n]);
      }
    __builtin_amdgcn_s_setprio(0);
    BAR();

    // ---- phase 2: Q1 (m0-3 x n2-3) ----
#pragma unroll
    for (int n = 2; n < 4; ++n) { b[n][0] = ldB(c, n, 0); b[n][1] = ldB(c, n, 1); }
    if (T + 1 < NT_) stage(2, T + 1);
    BAR(); LGKM0();
    __builtin_amdgcn_s_setprio(1);
#pragma unroll
    for (int m = 0; m < 4; ++m)
#pragma unroll
      for (int n = 2; n < 4; ++n) {
        acc[m][n] = MFMA(a[m][0], b[n][0], acc[m][n]);
        acc[m][n] = MFMA(a[m][1], b[n][1], acc[m][n]);
      }
    __builtin_amdgcn_s_setprio(0);
    BAR();

    // ---- phase 3: Q2 (m4-7 x n0-1) ----
#pragma unroll
    for (int m = 0; m < 4; ++m) { a[m][0] = ldA(c, m + 4, 0); a[m][1] = ldA(c, m + 4, 1); }
    if (T + 1 < NT_) stage(3, T + 1);
    BAR(); LGKM0();
    __builtin_amdgcn_s_setprio(1);
#pragma unroll
    for (int m = 0; m < 4; ++m)
#pragma unroll
      for (int n = 0; n < 2; ++n) {
        acc[m + 4][n] = MFMA(a[m][0], b[n][0], acc[m + 4][n]);
        acc[m + 4][n] = MFMA(a[m][1], b[n][1], acc[m + 4][n]);
      }
    __builtin_amdgcn_s_setprio(0);
    BAR();

    // ---- phase 4: Q3 (m4-7 x n2-3) ----
    if (T + 2 < NT_) stage(0, T + 2);
    BAR();
    __builtin_amdgcn_s_setprio(1);
#pragma unroll
    for (int m = 0; m < 4; ++m)
#pragma unroll
      for (int n = 2; n < 4; ++n) {
        acc[m + 4][n] = MFMA(a[m][0], b[n][0], acc[m + 4][n]);
        acc[m + 4][n] = MFMA(a[m][1], b[n][1], acc[m + 4][n]);
      }
    __builtin_amdgcn_s_setprio(0);
    if (T < NT_ - 2) { VM2(); } else { VM0(); }
    BAR();
  }

  // epilogue: C/D layout col=lane&15, row=(lane>>4)*4+j (m89/m91)
  const int orow = (lane >> 4) * 4, ocol = lane & 15;
  const int rbase = row0 + mi * 256 + wm * 128;
  const int cbase = ni * 256 + wn * 64;
#pragma unroll
  for (int m = 0; m < 8; ++m)
#pragma unroll
    for (int n = 0; n < 4; ++n)
#pragma unroll
      for (int j = 0; j < 4; ++j)
        C[(size_t)(rbase + m * 16 + orow + j) * NOUT + (cbase + n * 16 + ocol)] =
            acc[m][n][j];
}

// ============================================================
extern "C" void kernel_launch(void* const* d_in, const int* in_sizes, int n_in,
                              void* d_out, int out_size, void* d_ws, size_t ws_size,
                              hipStream_t stream) {
  const float* x    = (const float*)d_in[0];
  const float* Wenc = (const float*)d_in[1];
  const float* Wdec = (const float*)d_in[2];
  const float* Wout = (const float*)d_in[3];
  float* out = (float*)d_out;

  char* ws = (char*)d_ws;
  bf16*  Wb = (bf16*)ws;                          // 8 MiB
  float* z  = (float*)(ws + 8388608);             // 1 MiB
  bf16*  h  = (bf16*)(ws + 8388608 + 1048576);    // up to 256 MiB

  const size_t head = 8388608 + 1048576;
  const size_t avail = ws_size > head ? ws_size - head : 0;
  int nch = 1;
  while (nch < 128 && (size_t)(MROWS / nch) * FFN_ * 2 > avail) nch <<= 1;
  const int chunk = MROWS / nch;   // multiple of 256

  k_wcvt<<<4096, 256, 0, stream>>>(Wout, Wb);
  k_encode<<<2048, 256, 0, stream>>>(x, Wenc, z);
  for (int c = 0; c < nch; ++c) {
    const int row0 = c * chunk;
    dim3 hg(chunk / 64, 2);
    k_hgen<<<hg, 256, 0, stream>>>(z, Wdec, h, row0);
    k_gemm8<<<(chunk / 256) * 4, 512, 0, stream>>>(h, Wb, out, row0);
  }
}

// Round 5
// 372.830 us; speedup vs baseline: 1.6026x; 1.0460x over previous
//
#include <hip/hip_runtime.h>
#include <hip/hip_bf16.h>
#include <stdint.h>

typedef __bf16 bf16;
typedef bf16 bf16x8 __attribute__((ext_vector_type(8)));
typedef bf16 bf16x4 __attribute__((ext_vector_type(4)));
typedef float f32x4 __attribute__((ext_vector_type(4)));

#define NQ_    8
#define EMBED_ 1024
#define FFN_   4096
#define MROWS  32768   // B*S = 8*4096
#define NOUT   1024    // EMBED
#define NT_    (FFN_ / 64)   // 64 K-tiles of BK=64

// ---- async global->LDS, 16B per lane, wave-uniform LDS base ----
__device__ __forceinline__ void gl_lds16(const bf16* g, bf16* l) {
  __builtin_amdgcn_global_load_lds(
      (__attribute__((address_space(1))) void*)(const_cast<bf16*>(g)),
      (__attribute__((address_space(3))) void*)l, 16, 0, 0);
}

#define BAR()   __builtin_amdgcn_s_barrier()
#define LGKM0() asm volatile("s_waitcnt lgkmcnt(0)" ::: "memory")
#define VM2()   asm volatile("s_waitcnt vmcnt(2)" ::: "memory")
#define VM0()   asm volatile("s_waitcnt vmcnt(0)" ::: "memory")
#define MFMA(a, b, c) __builtin_amdgcn_mfma_f32_16x16x32_bf16((a), (b), (c), 0, 0, 0)

// ============================================================
// Kernel 1: W_out f32 -> bf16
// ============================================================
__global__ __launch_bounds__(256) void k_wcvt(const float* __restrict__ w,
                                              bf16* __restrict__ wb) {
  const int i = (blockIdx.x * 256 + threadIdx.x) * 4;
  const float4 v = *(const float4*)(w + i);
  bf16x4 o;
  o[0] = (bf16)v.x; o[1] = (bf16)v.y; o[2] = (bf16)v.z; o[3] = (bf16)v.w;
  *(bf16x4*)(wb + i) = o;
}

// ============================================================
// Kernel 2: theta = x @ W_enc^T ; z = analytic circuit expvals
//   z_0 = prod_{w=1..7} cos(theta_w); z_k = prod_{w=0..k} cos(theta_w)
// ============================================================
__global__ __launch_bounds__(256) void k_encode(const float* __restrict__ x,
                                                const float* __restrict__ Wenc,
                                                float* __restrict__ z) {
  const int t = threadIdx.x;
  const int wave = t >> 6, lane = t & 63;
  const int r0 = blockIdx.x * 16;

  float4 we[8];
#pragma unroll
  for (int q = 0; q < 8; ++q)
    we[q] = *(const float4*)(Wenc + q * EMBED_ + t * 4);

  __shared__ float red[16][4][8];
  __shared__ float cb[16][8];

  for (int rr = 0; rr < 16; ++rr) {
    const float4 xv = *(const float4*)(x + (size_t)(r0 + rr) * EMBED_ + t * 4);
#pragma unroll
    for (int q = 0; q < 8; ++q) {
      float v = xv.x * we[q].x + xv.y * we[q].y + xv.z * we[q].z + xv.w * we[q].w;
#pragma unroll
      for (int off = 32; off > 0; off >>= 1) v += __shfl_xor(v, off, 64);
      if (lane == 0) red[rr][wave][q] = v;
    }
  }
  __syncthreads();
  if (t < 128) {
    const int rr = t >> 3, q = t & 7;
    const float th = red[rr][0][q] + red[rr][1][q] + red[rr][2][q] + red[rr][3][q];
    cb[rr][q] = cosf(th);
  }
  __syncthreads();
  if (t < 16) {
    float c[8];
#pragma unroll
    for (int q = 0; q < 8; ++q) c[q] = cb[t][q];
    float zz[8];
    zz[0] = c[1] * c[2] * c[3] * c[4] * c[5] * c[6] * c[7];
    float p = c[0];
#pragma unroll
    for (int k = 1; k < 8; ++k) { p *= c[k]; zz[k] = p; }
    float4* zp = (float4*)(z + (size_t)(r0 + t) * 8);
    zp[0] = make_float4(zz[0], zz[1], zz[2], zz[3]);
    zp[1] = make_float4(zz[4], zz[5], zz[6], zz[7]);
  }
}

// ============================================================
// Kernel 3: h = relu(z @ W_dec^T) -> bf16 [chunk_rows][4096]
// ============================================================
__global__ __launch_bounds__(256) void k_hgen(const float* __restrict__ z,
                                              const float* __restrict__ Wdec,
                                              bf16* __restrict__ h,
                                              int row0) {
  const int t = threadIdx.x;
  const int f0 = blockIdx.y * 2048 + t * 8;
  const int g0 = row0 + blockIdx.x * 64;
  const int l0 = blockIdx.x * 64;

  float4 wd[16];
#pragma unroll
  for (int i = 0; i < 16; ++i)
    wd[i] = *(const float4*)(Wdec + (size_t)f0 * 8 + i * 4);

  for (int rr = 0; rr < 64; ++rr) {
    const float4* zp = (const float4*)(z + (size_t)(g0 + rr) * 8);
    const float4 z0 = zp[0], z1 = zp[1];
    bf16x8 o;
#pragma unroll
    for (int j = 0; j < 8; ++j) {
      const float4 a = wd[j * 2], b = wd[j * 2 + 1];
      float s = a.x * z0.x + a.y * z0.y + a.z * z0.z + a.w * z0.w +
                b.x * z1.x + b.y * z1.y + b.z * z1.z + b.w * z1.w;
      o[j] = (bf16)fmaxf(s, 0.0f);
    }
    *(bf16x8*)(h + (size_t)(l0 + rr) * FFN_ + f0) = o;
  }
}

// ============================================================
// Kernel 4: out = h @ W_out^T — 256x256xBK64 8-phase schedule
// (T1 XCD-swizzle + T2 full 3-bit slot swizzle + T3/T4 counted vmcnt + T5 setprio)
// Swizzle: LDS slot (16B) s' = s ^ (row&7), applied as pre-swizzled global
// source on the write side and XOR on the ds_read side (involution).
// Per 8-lane ds_read_b128 retire group, slots (l>>4)^(l&7) cover all 8 ->
// all 32 banks -> conflict-free (was 1-bit: 4-way, 2.5e7 conflicts @ r4).
// ============================================================
__global__ __launch_bounds__(512, 2) void k_gemm8(const bf16* __restrict__ A,
                                                  const bf16* __restrict__ Bt,
                                                  float* __restrict__ C,
                                                  int row0) {
  __shared__ bf16 lds[65536];  // 128 KiB: buf c at c*32768 elems = [A 16384 | B 16384]

  // bijective XCD swizzle (m204)
  const int nwg = (int)gridDim.x, orig = (int)blockIdx.x;
  const int qd = nwg >> 3, rm = nwg & 7;
  const int xcd = orig & 7;
  const int bid = (xcd < rm ? xcd * (qd + 1) : rm * (qd + 1) + (xcd - rm) * qd) + (orig >> 3);
  const int mi = bid >> 2, ni = bid & 3;

  const int t = threadIdx.x;
  const int wave = t >> 6, lane = t & 63;
  const int wm = wave >> 2, wn = wave & 3;

  // staging geometry: chunk q = i*512 + t ; row = q>>3 ; slot = q&7
  // source pre-swizzle: fetch global slot (q&7) ^ (row&7) into linear LDS slot
  const int qrow0 = t >> 3;
  const int qc8 = (t & 7) ^ ((t >> 3) & 7);
  const size_t Abase = (size_t)(mi * 256) * FFN_;
  const size_t Bbase = (size_t)(ni * 256) * FFN_;
  const int wbase = wave * 512;                // wave-uniform LDS base (1024 B/wave)

  const int fr = lane & 15, fk = (lane >> 4) * 8;

  f32x4 acc[8][4] = {};

  auto stage = [&](int s, int T1) {            // s: 0=A rows 0-127, 1=A 128-255, 2=B 0-127, 3=B 128-255
    const int c = T1 & 1;
    const bf16* G = (s < 2) ? A : Bt;
    const size_t gb = ((s < 2) ? Abase : Bbase) + (size_t)((s & 1) * 128) * FFN_ + T1 * 64;
    bf16* L = (bf16*)lds + c * 32768 + ((s < 2) ? 0 : 16384) + (s & 1) * 8192 + wbase;
#pragma unroll
    for (int i = 0; i < 2; ++i) {
      const int row = i * 64 + qrow0;          // row&7 == qrow0&7 (i*64 ≡ 0 mod 8)
      gl_lds16(G + gb + (size_t)row * FFN_ + qc8 * 8, L + i * 4096);
    }
  };
  auto ldA = [&](int c, int m, int kk) -> bf16x8 {   // read swizzle: slot ^= row&7
    const int row = wm * 128 + m * 16 + fr;
    const int off = (row * 64 + kk * 32 + fk) ^ ((row & 7) << 3);
    return *(const bf16x8*)((const bf16*)lds + c * 32768 + off);
  };
  auto ldB = [&](int c, int n, int kk) -> bf16x8 {
    const int row = wn * 64 + n * 16 + fr;
    const int off = (row * 64 + kk * 32 + fk) ^ ((row & 7) << 3);
    return *(const bf16x8*)((const bf16*)lds + c * 32768 + 16384 + off);
  };

  // prologue: tile0 fully + s0 of tile1; wait tile0 (leave 2 in flight)
  stage(0, 0); stage(1, 0); stage(2, 0); stage(3, 0);
  stage(0, 1);
  VM2();
  BAR();

#pragma unroll 2
  for (int T = 0; T < NT_; ++T) {
    const int c = T & 1;
    bf16x8 a[4][2], b[4][2];

    // ---- phase 1: Q0 (m0-3 x n0-1) ----
#pragma unroll
    for (int m = 0; m < 4; ++m) { a[m][0] = ldA(c, m, 0); a[m][1] = ldA(c, m, 1); }
#pragma unroll
    for (int n = 0; n < 2; ++n) { b[n][0] = ldB(c, n, 0); b[n][1] = ldB(c, n, 1); }
    if (T + 1 < NT_) stage(1, T + 1);
    BAR(); LGKM0();
    __builtin_amdgcn_s_setprio(1);
#pragma unroll
    for (int m = 0; m < 4; ++m)
#pragma unroll
      for (int n = 0; n < 2; ++n) {
        acc[m][n] = MFMA(a[m][0], b[n][0], acc[m][n]);
        acc[m][n] = MFMA(a[m][1], b[n][1], acc[m][n]);
      }
    __builtin_amdgcn_s_setprio(0);
    BAR();

    // ---- phase 2: Q1 (m0-3 x n2-3) ----
#pragma unroll
    for (int n = 2; n < 4; ++n) { b[n][0] = ldB(c, n, 0); b[n][1] = ldB(c, n, 1); }
    if (T + 1 < NT_) stage(2, T + 1);
    BAR(); LGKM0();
    __builtin_amdgcn_s_setprio(1);
#pragma unroll
    for (int m = 0; m < 4; ++m)
#pragma unroll
      for (int n = 2; n < 4; ++n) {
        acc[m][n] = MFMA(a[m][0], b[n][0], acc[m][n]);
        acc[m][n] = MFMA(a[m][1], b[n][1], acc[m][n]);
      }
    __builtin_amdgcn_s_setprio(0);
    BAR();

    // ---- phase 3: Q2 (m4-7 x n0-1) ----
#pragma unroll
    for (int m = 0; m < 4; ++m) { a[m][0] = ldA(c, m + 4, 0); a[m][1] = ldA(c, m + 4, 1); }
    if (T + 1 < NT_) stage(3, T + 1);
    BAR(); LGKM0();
    __builtin_amdgcn_s_setprio(1);
#pragma unroll
    for (int m = 0; m < 4; ++m)
#pragma unroll
      for (int n = 0; n < 2; ++n) {
        acc[m + 4][n] = MFMA(a[m][0], b[n][0], acc[m + 4][n]);
        acc[m + 4][n] = MFMA(a[m][1], b[n][1], acc[m + 4][n]);
      }
    __builtin_amdgcn_s_setprio(0);
    BAR();

    // ---- phase 4: Q3 (m4-7 x n2-3) ----
    if (T + 2 < NT_) stage(0, T + 2);
    BAR();
    __builtin_amdgcn_s_setprio(1);
#pragma unroll
    for (int m = 0; m < 4; ++m)
#pragma unroll
      for (int n = 2; n < 4; ++n) {
        acc[m + 4][n] = MFMA(a[m][0], b[n][0], acc[m + 4][n]);
        acc[m + 4][n] = MFMA(a[m][1], b[n][1], acc[m + 4][n]);
      }
    __builtin_amdgcn_s_setprio(0);
    if (T < NT_ - 2) { VM2(); } else { VM0(); }
    BAR();
  }

  // epilogue: C/D layout col=lane&15, row=(lane>>4)*4+j (m89/m91)
  const int orow = (lane >> 4) * 4, ocol = lane & 15;
  const int rbase = row0 + mi * 256 + wm * 128;
  const int cbase = ni * 256 + wn * 64;
#pragma unroll
  for (int m = 0; m < 8; ++m)
#pragma unroll
    for (int n = 0; n < 4; ++n)
#pragma unroll
      for (int j = 0; j < 4; ++j)
        C[(size_t)(rbase + m * 16 + orow + j) * NOUT + (cbase + n * 16 + ocol)] =
            acc[m][n][j];
}

// ============================================================
extern "C" void kernel_launch(void* const* d_in, const int* in_sizes, int n_in,
                              void* d_out, int out_size, void* d_ws, size_t ws_size,
                              hipStream_t stream) {
  const float* x    = (const float*)d_in[0];
  const float* Wenc = (const float*)d_in[1];
  const float* Wdec = (const float*)d_in[2];
  const float* Wout = (const float*)d_in[3];
  float* out = (float*)d_out;

  char* ws = (char*)d_ws;
  bf16*  Wb = (bf16*)ws;                          // 8 MiB
  float* z  = (float*)(ws + 8388608);             // 1 MiB
  bf16*  h  = (bf16*)(ws + 8388608 + 1048576);    // up to 256 MiB

  const size_t head = 8388608 + 1048576;
  const size_t avail = ws_size > head ? ws_size - head : 0;
  int nch = 1;
  while (nch < 128 && (size_t)(MROWS / nch) * FFN_ * 2 > avail) nch <<= 1;
  const int chunk = MROWS / nch;   // multiple of 256

  k_wcvt<<<4096, 256, 0, stream>>>(Wout, Wb);
  k_encode<<<2048, 256, 0, stream>>>(x, Wenc, z);
  for (int c = 0; c < nch; ++c) {
    const int row0 = c * chunk;
    dim3 hg(chunk / 64, 2);
    k_hgen<<<hg, 256, 0, stream>>>(z, Wdec, h, row0);
    k_gemm8<<<(chunk / 256) * 4, 512, 0, stream>>>(h, Wb, out, row0);
  }
}